// Round 9
// baseline (171.476 us; speedup 1.0000x reference)
//
#include <hip/hip_runtime.h>

// DownSample (fp32 in/out, bf16 MFMA internals), MI355X gfx950
// Shapes: B=128, n_stk=32, n_stk_pnt=32, COOR=32, m=16, k=2
// outputs: sparse_out [128,256,16] | dense_out [128,128,16,16] | coor_out [128,16,32]
//
// R17: 2-m software-pipelined dense blocks (no asm, no manual vmcnt -- R16's
// manual counter bookkeeping raced with compiler vmem and crashed; reverted).
// Overlap comes only from compiler-safe mechanisms: (a) mB gather loads issued
// before barrier B1, consumed after B2 (barrier fence pins them; latency hides
// under MLP(mA)); (b) conv(mA) and MLP(mB) fused into ONE loop with two
// independent MFMA chains per iteration. 5 barriers per 2 m. LDS 36352:
// Vb0|Vb1 16.9KB each (Bc aliases the dead Vb), Pd 2.5KB -> 4 blocks/CU.
// All loop bodies copied from verified R14. Sparse path = R14 verbatim.

typedef unsigned short u16;
typedef unsigned int   u32;
typedef __attribute__((ext_vector_type(8))) short bf16x8;   // 4 VGPRs
typedef __attribute__((ext_vector_type(4))) float f32x4;

#define BN_SCALE 0.9999950000374997f   // 1/sqrt(1+1e-5)

__device__ __forceinline__ float gelu_f(float x){
  return 0.5f*x*(1.0f + erff(x*0.70710678118654752f));
}
__device__ __forceinline__ u16 f2bf(float f){
  u32 x = __float_as_uint(f);
  x += 0x7fffu + ((x>>16)&1u);           // RNE
  return (u16)(x>>16);
}
#define MFMA16(a,b,c) __builtin_amdgcn_mfma_f32_16x16x32_bf16(a,b,c,0,0,0)

// pack one float4-pair (channels C,C+1; x positions X..X+3) into Vb layout
#define PACK8(VB, fcL, fnL, fcH, fnH, C, X) do{                                   \
  _Pragma("unroll") for (int e=0;e<4;e++){                                        \
    int xx=(X)+e, dp=xx&1, p=xx>>1;                                               \
    u32 dv = (u32)f2bf(((const float*)&(fnL))[e]-((const float*)&(fcL))[e])       \
           | ((u32)f2bf(((const float*)&(fnH))[e]-((const float*)&(fcH))[e])<<16);\
    u32 cv = (u32)f2bf(((const float*)&(fcL))[e])                                 \
           | ((u32)f2bf(((const float*)&(fcH))[e])<<16);                          \
    *(u32*)&(VB)[p*264 + dp*128 + (C)]      = dv;                                 \
    *(u32*)&(VB)[(16+p)*264 + dp*128 + (C)] = cv;                                 \
  } }while(0)

// bn+gelu+max_k epilogue, scatter S[o][p] -> im2col BC[x][o*3+tap]
#define EPI1(ACC, BC) do{                                                         \
  _Pragma("unroll") for (int r=0;r<2;r++){                                        \
    _Pragma("unroll") for (int pt=0;pt<2;pt++){                                   \
      _Pragma("unroll") for (int reg=0;reg<4;reg++){                              \
        int o=(wv+r*4)*16+quad*4+reg; int p=pt*16+col;                            \
        float val=gelu_f(fmaf((ACC)[r][pt][reg], Pd[o], Pd[128+o]));              \
        if (pt==0) val=fmaxf(val, Pd[512+o]);                                     \
        u16 bv=f2bf(val);                                                         \
        if (p&1){ (BC)[((p-1)>>1)*392+o*3+2]=bv;                                  \
                  if(p<31)(BC)[((p+1)>>1)*392+o*3+0]=bv; }                        \
        else    { (BC)[(p>>1)*392+o*3+1]=bv; }                                    \
      } } } }while(0)

#define EPI2(CACC, MM) do{                                                        \
  _Pragma("unroll") for (int r=0;r<2;r++){                                        \
    _Pragma("unroll") for (int reg=0;reg<4;reg++){                                \
      int o=(wv+r*4)*16+quad*4+reg;                                               \
      float val=gelu_f(fmaf((CACC)[r][reg], Pd[256+o], Pd[384+o]));               \
      out_dn[(b*128+o)*256 + (MM)*16 + col]=val;                                  \
    } } }while(0)

// ---------------- kernel 1: weight swizzle (blocks 0..831) + FPS (832..959) ----------------
// A-frag layout: afrag[(kt*NT + ot)*64 + lane][j] = W[o = ot*16+(lane&15)][k = kt*32+((lane>>4)&3)*8+j]
__global__ __launch_bounds__(256) void k_prep(
    const float* __restrict__ dn_w, const float* __restrict__ ds_w, const float* __restrict__ sp_w,
    const float* __restrict__ coor,
    u16* __restrict__ wdb, u16* __restrict__ wcb, u16* __restrict__ wsb,
    int* __restrict__ fps_idx, int* __restrict__ nn_idx, float* __restrict__ coor_out)
{
  int blk = blockIdx.x, t = threadIdx.x;
  if (blk < 128){                       // dense MLP W [128o x 256k] -> 8kt x 8ot
    int w = blk*256 + t;
    int j=w&7, lane=(w>>3)&63, tile=w>>9;
    int kt=tile>>3, ot=tile&7;
    int o=ot*16+(lane&15), i=kt*32+((lane>>4)&3)*8+j;
    wdb[w] = f2bf(dn_w[o*256+i]);
  } else if (blk < 320){                // conv W [128o x 384k] -> 12kt x 8ot
    int w = (blk-128)*256 + t;
    int j=w&7, lane=(w>>3)&63, tile=w>>9;
    int kt=tile>>3, ot=tile&7;
    int o=ot*16+(lane&15), k=kt*32+((lane>>4)&3)*8+j;
    wcb[w] = f2bf(ds_w[o*384+k]);
  } else if (blk < 832){                // sparse W [256o x 512k] -> 16kt x 16ot
    int w = (blk-320)*256 + t;
    int j=w&7, lane=(w>>3)&63, tile=w>>9;
    int kt=tile>>4, ot=tile&15;
    int o=ot*16+(lane&15), i=kt*32+((lane>>4)&3)*8+j;
    wsb[w] = f2bf(sp_w[o*512+i]);
  } else {
    // ---- FPS + NN + coor_out for b = blk-832 ----
    int b = blk - 832;
    __shared__ float Xs[32*33];
    __shared__ float D[32*33];
    __shared__ int   s_sel[16];
    for (int i=t;i<1024;i+=256) Xs[(i>>5)*33 + (i&31)] = coor[b*1024+i];
    __syncthreads();
    #pragma unroll
    for (int k2=0;k2<4;k2++){
      int p=t+k2*256, i=p>>5, j=p&31;
      float d=0.f;
      #pragma unroll
      for (int c=0;c<32;c++){ float df=Xs[i*33+c]-Xs[j*33+c]; d+=df*df; }
      D[i*33+j]=d;
    }
    __syncthreads();
    if (t < 64){
      int j = t & 31;
      float dist = 3.0e38f;
      int far = 0;
      #pragma unroll
      for (int it=0; it<16; ++it){
        if (t==0) s_sel[it]=far;
        dist = fminf(dist, D[far*33+j]);
        float v=dist; int idx=j;              // argmax, first-index tie-break
        #pragma unroll
        for (int off=16; off>=1; off>>=1){
          float v2=__shfl_xor(v,off,32); int i2=__shfl_xor(idx,off,32);
          if (v2>v || (v2==v && i2<idx)){ v=v2; idx=i2; }
        }
        far = idx;
      }
      if (t==0){
        #pragma unroll
        for (int it=0;it<16;++it) fps_idx[b*16+it]=s_sel[it];
      }
    }
    __syncthreads();
    {
      int wv=t>>6, j=t&31;
      #pragma unroll
      for (int q=0;q<4;q++){
        int it = wv*4+q, sel = s_sel[it];
        float d = D[sel*33+j];
        if (j==sel) d=3.0e38f;
        float v=d; int idx=j;                 // argmin, first-index tie-break
        #pragma unroll
        for (int off=16; off>=1; off>>=1){
          float v2=__shfl_xor(v,off,32); int i2=__shfl_xor(idx,off,32);
          if (v2<v || (v2==v && i2<idx)){ v=v2; idx=i2; }
        }
        if ((t&63)==0) nn_idx[b*16+it]=idx;
      }
    }
    for (int q=t;q<512;q+=256){
      int mm=q>>5, c=q&31;
      coor_out[b*512+q] = Xs[s_sel[mm]*33 + c];
    }
  }
}

// ---------------- kernel 2: fused sparse (blocks 0..127, 1 b each) + dense (128..1151, 2 m each) ----
__global__ __launch_bounds__(256) void k_main(
    const float* __restrict__ sfea, const u16* __restrict__ wsb,
    const float* __restrict__ sp_b, const float* __restrict__ sp_g, const float* __restrict__ sp_be,
    const float* __restrict__ dfea, const u16* __restrict__ wdb,
    const float* __restrict__ dn_b, const float* __restrict__ dn_g, const float* __restrict__ dn_be,
    const u16* __restrict__ wcb,
    const float* __restrict__ ds_b, const float* __restrict__ ds_g, const float* __restrict__ ds_be,
    const int* __restrict__ fps_idx, const int* __restrict__ nn_idx,
    float* __restrict__ out_sp, float* __restrict__ out_dn)
{
  __shared__ char smem[36352];
  __shared__ int SI[32];
  int blk=blockIdx.x;
  int t=threadIdx.x, lane=t&63, wv=t>>6, quad=lane>>4, col=lane&15;
  if (blk < 128){
    // ======== sparse: b = blk; C = W[256o x 512i] * X[512i x 16m]  (R14 verbatim) ========
    int b = blk;
    u16*   Xb = (u16*)smem;                      // [16m][520] u16 = 16640 B
    float* P  = (float*)(smem+16640);            // spA | spB : 512 f32 = 2048 B
    if (t<32){
      SI[t] = ((t<16) ? fps_idx[b*16+t] : nn_idx[b*16+(t-16)]) & 31;
    }
    { float A = sp_g[t]*BN_SCALE; P[t]=A; P[256+t]=fmaf(sp_b[t],A,sp_be[t]); }
    __syncthreads();
    {
      const float* row = sfea + b*8192 + t*32;   // channel t
      #pragma unroll 1
      for (int m=0;m<16;m++){
        float vc=row[SI[m]], vn=row[SI[16+m]];
        Xb[m*520 + t]       = f2bf(vn-vc);   // i<256: diff
        Xb[m*520 + 256 + t] = f2bf(vc);      // i>=256: ctr
      }
    }
    __syncthreads();
    #pragma unroll 1
    for (int oh=0;oh<2;oh++){
      f32x4 accA[2]={}, accB[2]={};              // [r]
      #pragma unroll 1
      for (int kt=0;kt<8;kt++){
        bf16x8 bf0 = *(const bf16x8*)&Xb[col*520 + kt*32 + quad*8];
        bf16x8 a0  = *(const bf16x8*)&wsb[((kt*16 + oh*8 + wv    )*64+lane)*8];
        bf16x8 a1  = *(const bf16x8*)&wsb[((kt*16 + oh*8 + wv + 4)*64+lane)*8];
        accA[0]=MFMA16(a0,bf0,accA[0]); accA[1]=MFMA16(a1,bf0,accA[1]);
      }
      #pragma unroll 1
      for (int kt=8;kt<16;kt++){
        bf16x8 bf0 = *(const bf16x8*)&Xb[col*520 + kt*32 + quad*8];
        bf16x8 a0  = *(const bf16x8*)&wsb[((kt*16 + oh*8 + wv    )*64+lane)*8];
        bf16x8 a1  = *(const bf16x8*)&wsb[((kt*16 + oh*8 + wv + 4)*64+lane)*8];
        accB[0]=MFMA16(a0,bf0,accB[0]); accB[1]=MFMA16(a1,bf0,accB[1]);
      }
      #pragma unroll
      for (int r=0;r<2;r++){
        #pragma unroll
        for (int reg=0;reg<4;reg++){
          int o = oh*128 + (wv+r*4)*16 + quad*4 + reg;
          float A=P[o], Bv=P[256+o];
          float k1 = accA[r][reg]+accB[r][reg];  // k=1: [diff|ctr]
          float k0 = accB[r][reg];               // k=0: diff part exactly 0
          float v = fmaxf(gelu_f(fmaf(k1,A,Bv)), gelu_f(fmaf(k0,A,Bv)));
          out_sp[(b*256+o)*16 + col] = v;
        }
      }
    }
  } else {
    // ======== dense: d=blk-128; b=((d>>6)<<3)|(d&7); m0=((d>>3)&7)*2; 2 m pipelined ========
    int d=blk-128;
    int b = ((d>>6)<<3) | (d&7), m0 = ((d>>3)&7)*2;
    u16* Vb0 = (u16*)smem;                // mA X-panel [32p][264] = 16896 B; later Bc0 [16x][392]=12544
    u16* Vb1 = (u16*)(smem+16896);        // mB X-panel; later Bc1
    u16* Bc0 = Vb0;
    u16* Bc1 = Vb1;
    float* Pd = (float*)(smem+33792);     // dnA|dnB|dsA|dsB|a0 : 640 f32 = 2560 B
    int ciA=fps_idx[b*16+m0]&31,   niA=nn_idx[b*16+m0]&31;
    int ciB=fps_idx[b*16+m0+1]&31, niB=nn_idx[b*16+m0+1]&31;
    if (t < 128){                         // fold BN: out = gelu(acc*A + B)
      float A  = dn_g[t]*BN_SCALE; float Bv = fmaf(dn_b[t], A, dn_be[t]);
      float Ac = ds_g[t]*BN_SCALE; float Cv = fmaf(ds_b[t], Ac, ds_be[t]);
      Pd[t]=A; Pd[128+t]=Bv; Pd[256+t]=Ac; Pd[384+t]=Cv;
      Pd[512+t]=gelu_f(Bv);               // a0 (k=0 diff value)
    }
    const float* Db = dfea + b*131072;    // dfea[b][c][s][x]: c*1024 + s*32 + x
    int c0=(t>>3)*2,        x0=(t&7)*4;            // slice 0: threads cover c 0..62
    int w1=t+256; int c1=(w1>>3)*2, x1=(w1&7)*4;   // slice 1: c 64..126
    const float* base0 = Db + c0*1024 + x0;
    const float* base1 = Db + c1*1024 + x1;
    // ---- phase 1: stage mA -> Vb0; issue mB gathers into named regs ----
    {
      float4 fc=*(const float4*)(base0+ciA*32), fn=*(const float4*)(base0+niA*32);
      float4 gc=*(const float4*)(base0+1024+ciA*32), gn=*(const float4*)(base0+1024+niA*32);
      PACK8(Vb0, fc, fn, gc, gn, c0, x0);
      fc=*(const float4*)(base1+ciA*32); fn=*(const float4*)(base1+niA*32);
      gc=*(const float4*)(base1+1024+ciA*32); gn=*(const float4*)(base1+1024+niA*32);
      PACK8(Vb0, fc, fn, gc, gn, c1, x1);
    }
    float4 gB0=*(const float4*)(base0+ciB*32),      gB1=*(const float4*)(base0+niB*32);
    float4 gB2=*(const float4*)(base0+1024+ciB*32), gB3=*(const float4*)(base0+1024+niB*32);
    float4 gB4=*(const float4*)(base1+ciB*32),      gB5=*(const float4*)(base1+niB*32);
    float4 gB6=*(const float4*)(base1+1024+ciB*32), gB7=*(const float4*)(base1+1024+niB*32);
    __syncthreads();                                   // B1
    // ---- phase 2: MLP(mA) from Vb0 ----
    f32x4 accA[2][2]={};
    #pragma unroll 1
    for (int kt=0;kt<8;kt++){
      bf16x8 a0 = *(const bf16x8*)&wdb[((kt*8+wv  )*64+lane)*8];
      bf16x8 a1 = *(const bf16x8*)&wdb[((kt*8+wv+4)*64+lane)*8];
      bf16x8 b0 = *(const bf16x8*)&Vb0[col*264      + kt*32 + quad*8];
      bf16x8 b1 = *(const bf16x8*)&Vb0[(16+col)*264 + kt*32 + quad*8];
      accA[0][0]=MFMA16(a0,b0,accA[0][0]); accA[0][1]=MFMA16(a0,b1,accA[0][1]);
      accA[1][0]=MFMA16(a1,b0,accA[1][0]); accA[1][1]=MFMA16(a1,b1,accA[1][1]);
    }
    __syncthreads();                                   // B2  (Vb0 dead -> Bc0)
    // ---- phase 3: pack mB -> Vb1; epi1(mA) -> Bc0 ----
    PACK8(Vb1, gB0, gB1, gB2, gB3, c0, x0);
    PACK8(Vb1, gB4, gB5, gB6, gB7, c1, x1);
    if (t<128) Bc0[t*3] = 0;               // only unwritten im2col slot: x=0,tap0 (o=t)
    EPI1(accA, Bc0);
    __syncthreads();                                   // B3
    // ---- phase 4: conv(mA) from Bc0  ||  MLP(mB) from Vb1 (two independent chains) ----
    f32x4 cacc[2]={};
    f32x4 accB[2][2]={};
    #pragma unroll 1
    for (int kt=0;kt<12;kt++){
      bf16x8 cb0 = *(const bf16x8*)&Bc0[col*392 + kt*32 + quad*8];
      bf16x8 ca0 = *(const bf16x8*)&wcb[((kt*8+wv  )*64+lane)*8];
      bf16x8 ca1 = *(const bf16x8*)&wcb[((kt*8+wv+4)*64+lane)*8];
      cacc[0]=MFMA16(ca0,cb0,cacc[0]);
      cacc[1]=MFMA16(ca1,cb0,cacc[1]);
      if (kt<8){
        bf16x8 a0 = *(const bf16x8*)&wdb[((kt*8+wv  )*64+lane)*8];
        bf16x8 a1 = *(const bf16x8*)&wdb[((kt*8+wv+4)*64+lane)*8];
        bf16x8 b0 = *(const bf16x8*)&Vb1[col*264      + kt*32 + quad*8];
        bf16x8 b1 = *(const bf16x8*)&Vb1[(16+col)*264 + kt*32 + quad*8];
        accB[0][0]=MFMA16(a0,b0,accB[0][0]); accB[0][1]=MFMA16(a0,b1,accB[0][1]);
        accB[1][0]=MFMA16(a1,b0,accB[1][0]); accB[1][1]=MFMA16(a1,b1,accB[1][1]);
      }
    }
    __syncthreads();                                   // B4  (Vb1 dead -> Bc1)
    // ---- phase 5: epi1(mB) -> Bc1; epi2(mA) global stores ----
    if (t<128) Bc1[t*3] = 0;
    EPI1(accB, Bc1);
    EPI2(cacc, m0);
    __syncthreads();                                   // B5
    // ---- phase 6: conv(mB) from Bc1; epi2(mB) ----
    f32x4 cacc2[2]={};
    #pragma unroll 1
    for (int kt=0;kt<12;kt++){
      bf16x8 cb0 = *(const bf16x8*)&Bc1[col*392 + kt*32 + quad*8];
      bf16x8 ca0 = *(const bf16x8*)&wcb[((kt*8+wv  )*64+lane)*8];
      bf16x8 ca1 = *(const bf16x8*)&wcb[((kt*8+wv+4)*64+lane)*8];
      cacc2[0]=MFMA16(ca0,cb0,cacc2[0]);
      cacc2[1]=MFMA16(ca1,cb0,cacc2[1]);
    }
    EPI2(cacc2, m0+1);
  }
}

extern "C" void kernel_launch(void* const* d_in, const int* in_sizes, int n_in,
                              void* d_out, int out_size, void* d_ws, size_t ws_size,
                              hipStream_t stream) {
  const float* sparse_fea = (const float*)d_in[0];
  const float* dense_fea  = (const float*)d_in[1];
  const float* stk_coor   = (const float*)d_in[2];
  // d_in[3] = n_stk_center (16, hardcoded)
  const float* sp_w  = (const float*)d_in[4];
  const float* sp_b  = (const float*)d_in[5];
  const float* sp_g  = (const float*)d_in[6];
  const float* sp_be = (const float*)d_in[7];
  const float* dn_w  = (const float*)d_in[8];
  const float* dn_b  = (const float*)d_in[9];
  const float* dn_g  = (const float*)d_in[10];
  const float* dn_be = (const float*)d_in[11];
  const float* ds_w  = (const float*)d_in[12];
  const float* ds_b  = (const float*)d_in[13];
  const float* ds_g  = (const float*)d_in[14];
  const float* ds_be = (const float*)d_in[15];

  float* out = (float*)d_out;
  // outputs: sparse [0, 524288) | dense [524288, 4718592) | coor [4718592, 4784128)
  int* fps_idx = (int*)d_ws;                              // [0, 16384) B
  int* nn_idx  = fps_idx + 2048;
  u16* wdb = (u16*)((char*)d_ws + 16384);                 // 64 KB  (8kt x 8ot)
  u16* wcb = (u16*)((char*)d_ws + 81920);                 // 96 KB  (12kt x 8ot)
  u16* wsb = (u16*)((char*)d_ws + 180224);                // 256 KB (16kt x 16ot)

  k_prep<<<960, 256, 0, stream>>>(dn_w, ds_w, sp_w, stk_coor,
                                  wdb, wcb, wsb, fps_idx, nn_idx, out + 4718592);
  k_main<<<1152, 256, 0, stream>>>(sparse_fea, wsb, sp_b, sp_g, sp_be,
                                   dense_fea, wdb, dn_b, dn_g, dn_be,
                                   wcb, ds_b, ds_g, ds_be,
                                   fps_idx, nn_idx, out, out + 524288);
}